// Round 2
// baseline (16684.952 us; speedup 1.0000x reference)
//
#include <hip/hip_runtime.h>

#define NN   4096
#define OBSN 2048
#define S1   2047
#define S2   2047
#define HID  128
#define INDIM 100

// Barrier WITHOUT vmcnt(0) drain: only LDS ops must be visible across the
// workgroup. Global prefetches stay in flight across steps (the whole point).
// All cross-thread per-step dataflow is through LDS, so lgkmcnt(0) suffices.
__device__ __forceinline__ void bar() {
    asm volatile("s_waitcnt lgkmcnt(0)\n\ts_barrier" ::: "memory");
}

__device__ __forceinline__ float sigm(float x) {
    return 1.0f / (1.0f + __expf(-x));
}
__device__ __forceinline__ float tanh_(float x) {
    float e = __expf(2.0f * x);
    return 1.0f - 2.0f / (e + 1.0f);
}

// Exact reference-semantics cell classification (strict < on both sides,
// boundary-equality excluded via a+b==7).
__device__ __forceinline__ unsigned long long classify(float x, float y,
                                                       const float* bx, const float* by) {
    int a = 0, b = 0, c = 0, d = 0;
#pragma unroll
    for (int j = 0; j < 7; j++) {
        a += bx[j] < x;
        b += x < bx[j];
        c += by[j] < y;
        d += y < by[j];
    }
    if (a >= 1 && a <= 6 && (a + b) == 7 && c >= 1 && c <= 6 && (c + d) == 7)
        return 1ull << ((a - 1) * 6 + (c - 1));
    return 0ull;
}

// ---------- kernel 1: phase-1 occupancy masks (parallel over t) ----------
__global__ __launch_bounds__(256) void k_occ1(const float* __restrict__ obs,
                                              const float* __restrict__ oth,
                                              unsigned long long* __restrict__ occm) {
    const int t = blockIdx.x;
    const int slice = t + 1;
    const float cx = obs[slice * 2 + 0];
    const float cy = obs[slice * 2 + 1];
    const float CST[7] = {-1.5f, -1.0f, -0.5f, 0.0f, 0.5f, 1.0f, 1.5f};
    float bx[7], by[7];
#pragma unroll
    for (int j = 0; j < 7; j++) { bx[j] = CST[j] + cx; by[j] = CST[j] + cy; }

    const float2* p = (const float2*)(oth + (size_t)slice * NN * 2);
    unsigned long long m = 0ull;
#pragma unroll 4
    for (int i = 0; i < 16; i++) {
        float2 q = p[i * 256 + threadIdx.x];
        if (q.x > bx[0] && q.x < bx[6] && q.y > by[0] && q.y < by[6])
            m |= classify(q.x, q.y, bx, by);
    }
#pragma unroll
    for (int off = 32; off > 0; off >>= 1) m |= __shfl_down(m, off);
    __shared__ unsigned long long sm[4];
    if ((threadIdx.x & 63) == 0) sm[threadIdx.x >> 6] = m;
    __syncthreads();
    if (threadIdx.x == 0) occm[t] = sm[0] | sm[1] | sm[2] | sm[3];
}

// ---------- kernel 2: transpose occ columns of W_ih into [36][512] ----------
__global__ void k_tr(const float* __restrict__ W_ih, float* __restrict__ WT) {
    WT[blockIdx.x * 512 + threadIdx.x] = W_ih[threadIdx.x * INDIM + 64 + blockIdx.x];
}

// ---------- kernel 3: phase-1 gate preactivation G1[t][512] ----------
__global__ __launch_bounds__(256) void k_g1(const float* __restrict__ obs,
                                            const float* __restrict__ W_emb,
                                            const float* __restrict__ b_emb,
                                            const float* __restrict__ W_ih,
                                            const float* __restrict__ b_ih,
                                            const float* __restrict__ b_hh,
                                            const unsigned long long* __restrict__ occm,
                                            float* __restrict__ G1) {
    const int t = blockIdx.x;
    const int tid = threadIdx.x;
    __shared__ __align__(16) float e[64];
    const float d0 = obs[(t + 1) * 2 + 0] - obs[t * 2 + 0];
    const float d1 = obs[(t + 1) * 2 + 1] - obs[t * 2 + 1];
    if (tid < 64) {
        float v = W_emb[tid * 2 + 0] * d0 + W_emb[tid * 2 + 1] * d1 + b_emb[tid];
        e[tid] = v > 0.0f ? v : 0.0f;
    }
    __syncthreads();
    const unsigned long long m = occm[t];
#pragma unroll
    for (int rr = 0; rr < 2; rr++) {
        const int r = tid + rr * 256;
        const float* wr = W_ih + r * INDIM;
        float s = b_ih[r] + b_hh[r];
        float4 acc = {0.f, 0.f, 0.f, 0.f};
        const float4* w4 = (const float4*)wr;
        const float4* e4 = (const float4*)e;
#pragma unroll
        for (int q = 0; q < 16; q++) {
            float4 w = w4[q], ev = e4[q];
            acc.x += w.x * ev.x; acc.y += w.y * ev.y;
            acc.z += w.z * ev.z; acc.w += w.w * ev.w;
        }
        s += (acc.x + acc.y) + (acc.z + acc.w);
        unsigned long long mm = m;
        while (mm) {
            int j = __ffsll((long long)mm) - 1;
            mm &= mm - 1;
            s += wr[64 + j];
        }
        G1[t * 512 + r] = s;
    }
}

// ---------- kernel 4: sequential LSTM, 4-gates-per-unit + 2-way col split ----------
// Thread mapping: wv = tid>>6, lane = tid&63, unit u = wv*32 + (lane&31) in [0,128),
// col-half ch = lane>>5. Thread handles rows {u, u+128, u+256, u+384} = (i,f,g,o)
// restricted to h-cols [ch*64, ch*64+64) and e-cols [ch*32, ch*32+32).
// Partner lane^32 has the other column half; one __shfl_xor(·,32) completes each gate.
// Bias/occ/G1 contributions: ch0 owns rows i,f; ch1 owns rows g,o (added once/pair).
// Both pair-threads then compute identical (commutative-add) gates -> redundant c,h.
__global__ __launch_bounds__(256, 1) void k_seq(const float* __restrict__ obs,
                                                const float* __restrict__ oth,
                                                const float* __restrict__ W_emb,
                                                const float* __restrict__ b_emb,
                                                const float* __restrict__ W_ih,
                                                const float* __restrict__ b_ih,
                                                const float* __restrict__ W_hh,
                                                const float* __restrict__ b_hh,
                                                const float* __restrict__ W_out,
                                                const float* __restrict__ b_out,
                                                const float* __restrict__ G1,
                                                const float* __restrict__ WT,
                                                float* __restrict__ out) {
    const int tid  = threadIdx.x;
    const int wv   = tid >> 6;
    const int lane = tid & 63;
    const int u    = wv * 32 + (lane & 31);
    const int ch   = lane >> 5;

    // --- persistent weights (register/AGPR resident) ---
    float whh[4][64];   // W_hh rows {u,u+128,u+256,u+384}, cols [ch*64, +64)
    float wie[4][32];   // W_ih emb-cols [ch*32, +32)
    float biasg[4];
#pragma unroll
    for (int g = 0; g < 4; g++) {
        const int R = u + 128 * g;
        const float* s1 = W_hh + R * HID + ch * 64;
#pragma unroll
        for (int k = 0; k < 64; k++) whh[g][k] = s1[k];
        const float* s2 = W_ih + R * INDIM + ch * 32;
#pragma unroll
        for (int k = 0; k < 32; k++) wie[g][k] = s2[k];
        biasg[g] = ((g >> 1) == ch) ? (b_ih[R] + b_hh[R]) : 0.0f;
    }
    float wo0 = 0.f, wo1 = 0.f, wo2 = 0.f, wo3 = 0.f, wo4 = 0.f;
    if (ch == 0) {
        wo0 = W_out[0 * HID + u]; wo1 = W_out[1 * HID + u];
        wo2 = W_out[2 * HID + u]; wo3 = W_out[3 * HID + u];
        wo4 = W_out[4 * HID + u];
    }
    const float bo0 = b_out[0], bo1 = b_out[1];
    const float boT = (tid < 5) ? b_out[tid] : 0.0f;
    float we0 = 0.f, we1 = 0.f, be = 0.f;
    if (tid < 64) { we0 = W_emb[tid * 2]; we1 = W_emb[tid * 2 + 1]; be = b_emb[tid]; }
    const float obsA0 = obs[(S1 - 1) * 2], obsA1 = obs[(S1 - 1) * 2 + 1];
    const float obsB0 = obs[S1 * 2],       obsB1 = obs[S1 * 2 + 1];

    __shared__ __align__(16) float hbuf[2][HID];
    __shared__ __align__(16) float e_lds[64];
    __shared__ __align__(16) float red1[2][5][4];  // [parity][out-dim][wave]
    __shared__ __align__(16) float red2[5][4];
    __shared__ unsigned long long smask[4];

    if (tid < HID) hbuf[0][tid] = 0.0f;
    float c = 0.0f;
    float p1x = 0.f, p1y = 0.f, p2x = 0.f, p2y = 0.f;
    int p = 0;

    const int g1off = u + ch * 256;
    float g1a = G1[g1off], g1b = G1[g1off + 128];   // t=0 prefetch
    bar();

    // =============== phase 1: 1 barrier/step ===============
    for (int t = 0; t < S1; ++t) {
        const float ca = g1a, cb = g1b;
        const int tn = (t + 1 < S1) ? t + 1 : t;
        g1a = G1[tn * 512 + g1off];           // next-step prefetch, no barrier drains it
        g1b = G1[tn * 512 + g1off + 128];

        float4 a0 = {0,0,0,0}, a1 = {0,0,0,0}, a2 = {0,0,0,0}, a3 = {0,0,0,0};
        const float4* h4 = ((const float4*)hbuf[p]) + ch * 16;
#pragma unroll
        for (int q = 0; q < 16; q++) {
            const float4 hv = h4[q];
            a0.x += whh[0][4*q+0]*hv.x; a0.y += whh[0][4*q+1]*hv.y; a0.z += whh[0][4*q+2]*hv.z; a0.w += whh[0][4*q+3]*hv.w;
            a1.x += whh[1][4*q+0]*hv.x; a1.y += whh[1][4*q+1]*hv.y; a1.z += whh[1][4*q+2]*hv.z; a1.w += whh[1][4*q+3]*hv.w;
            a2.x += whh[2][4*q+0]*hv.x; a2.y += whh[2][4*q+1]*hv.y; a2.z += whh[2][4*q+2]*hv.z; a2.w += whh[2][4*q+3]*hv.w;
            a3.x += whh[3][4*q+0]*hv.x; a3.y += whh[3][4*q+1]*hv.y; a3.z += whh[3][4*q+2]*hv.z; a3.w += whh[3][4*q+3]*hv.w;
        }
        float pg0 = ((ch == 0) ? ca : 0.0f) + (a0.x + a0.y) + (a0.z + a0.w);
        float pg1 = ((ch == 0) ? cb : 0.0f) + (a1.x + a1.y) + (a1.z + a1.w);
        float pg2 = ((ch == 1) ? ca : 0.0f) + (a2.x + a2.y) + (a2.z + a2.w);
        float pg3 = ((ch == 1) ? cb : 0.0f) + (a3.x + a3.y) + (a3.z + a3.w);
        pg0 += __shfl_xor(pg0, 32);
        pg1 += __shfl_xor(pg1, 32);
        pg2 += __shfl_xor(pg2, 32);
        pg3 += __shfl_xor(pg3, 32);

        const float gi = sigm(pg0), gf = sigm(pg1);
        const float gg = tanh_(pg2), go = sigm(pg3);
        c = gf * c + gi * gg;
        const float h = go * tanh_(c);
        if (ch == 0) hbuf[p ^ 1][u] = h;

        float t0 = wo0 * h, t1 = wo1 * h, t2 = wo2 * h, t3 = wo3 * h, t4 = wo4 * h;
#pragma unroll
        for (int off = 16; off > 0; off >>= 1) {
            t0 += __shfl_down(t0, off); t1 += __shfl_down(t1, off);
            t2 += __shfl_down(t2, off); t3 += __shfl_down(t3, off);
            t4 += __shfl_down(t4, off);
        }
        if (lane == 0) {
            red1[p][0][wv] = t0; red1[p][1][wv] = t1; red1[p][2][wv] = t2;
            red1[p][3][wv] = t3; red1[p][4][wv] = t4;
        }
        bar();
        if (tid < 5) {
            const float4 r = ((const float4*)red1[p])[tid];
            out[t * 5 + tid] = (r.x + r.y) + (r.z + r.w) + boT;
        }
        if (t >= S1 - 2) {   // all threads capture handoff positions (uniform)
            const float4 r0 = ((const float4*)red1[p])[0];
            const float4 r1 = ((const float4*)red1[p])[1];
            const float n0 = (r0.x + r0.y) + (r0.z + r0.w) + bo0;
            const float n1 = (r1.x + r1.y) + (r1.z + r1.w) + bo1;
            if (t == S1 - 2) { p1x = obsA0 + n0; p1y = obsA1 + n1; }
            else             { p2x = obsB0 + n0; p2y = obsB1 + n1; }
        }
        p ^= 1;
    }

    // =============== phase 2: 2 barriers/step ===============
    float pcx = p2x, pcy = p2y;
    float dx = p2x - p1x, dy = p2y - p1y;

    float4 nb[8];
    {
        const float4* p4 = (const float4*)(oth + (size_t)OBSN * NN * 2);
#pragma unroll
        for (int i = 0; i < 8; i++) nb[i] = p4[i * 256 + tid];
    }
    const float CST[7] = {-1.5f, -1.0f, -0.5f, 0.0f, 0.5f, 1.0f, 1.5f};
    const float* wtb = WT + u + ch * 256;   // rows u+ch*256 (+128)

    for (int s = 0; s < S2; ++s) {
        float bx[7], by[7];
#pragma unroll
        for (int j = 0; j < 7; j++) { bx[j] = CST[j] + pcx; by[j] = CST[j] + pcy; }

        unsigned long long m = 0ull;
#pragma unroll
        for (int i = 0; i < 8; i++) {
            float4 q = nb[i];
            if (q.x > bx[0] && q.x < bx[6] && q.y > by[0] && q.y < by[6])
                m |= classify(q.x, q.y, bx, by);
            if (q.z > bx[0] && q.z < bx[6] && q.w > by[0] && q.w < by[6])
                m |= classify(q.z, q.w, bx, by);
        }
        {   // next-slice prefetch; no barrier drains it (lgkm-only barriers)
            const int sn = (s + 1 < S2) ? s + 1 : s;
            const float4* p4 = (const float4*)(oth + (size_t)(OBSN + sn) * NN * 2);
#pragma unroll
            for (int i = 0; i < 8; i++) nb[i] = p4[i * 256 + tid];
        }
#pragma unroll
        for (int off = 1; off < 64; off <<= 1) m |= __shfl_xor(m, off);
        if (lane == 0) smask[wv] = m;
        if (tid < 64) {
            float v = we0 * dx + we1 * dy + be;
            e_lds[tid] = v > 0.0f ? v : 0.0f;
        }
        bar();   // B1: smask + e_lds ready (h from prev step already visible)

        const unsigned long long mm = smask[0] | smask[1] | smask[2] | smask[3];
        float oa[6] = {0,0,0,0,0,0}, ob[6] = {0,0,0,0,0,0};
        unsigned long long m2 = mm;
#pragma unroll
        for (int i = 0; i < 6; i++) {   // issue occ-col loads early (L2, hidden by FMAs)
            if (m2) {
                const int j = __ffsll((long long)m2) - 1;
                m2 &= m2 - 1;
                oa[i] = wtb[j * 512];
                ob[i] = wtb[j * 512 + 128];
            }
        }

        float4 a0 = {0,0,0,0}, a1 = {0,0,0,0}, a2 = {0,0,0,0}, a3 = {0,0,0,0};
        {
            const float4* e4 = ((const float4*)e_lds) + ch * 8;
#pragma unroll
            for (int q = 0; q < 8; q++) {
                const float4 ev = e4[q];
                a0.x += wie[0][4*q+0]*ev.x; a0.y += wie[0][4*q+1]*ev.y; a0.z += wie[0][4*q+2]*ev.z; a0.w += wie[0][4*q+3]*ev.w;
                a1.x += wie[1][4*q+0]*ev.x; a1.y += wie[1][4*q+1]*ev.y; a1.z += wie[1][4*q+2]*ev.z; a1.w += wie[1][4*q+3]*ev.w;
                a2.x += wie[2][4*q+0]*ev.x; a2.y += wie[2][4*q+1]*ev.y; a2.z += wie[2][4*q+2]*ev.z; a2.w += wie[2][4*q+3]*ev.w;
                a3.x += wie[3][4*q+0]*ev.x; a3.y += wie[3][4*q+1]*ev.y; a3.z += wie[3][4*q+2]*ev.z; a3.w += wie[3][4*q+3]*ev.w;
            }
            const float4* h4 = ((const float4*)hbuf[p]) + ch * 16;
#pragma unroll
            for (int q = 0; q < 16; q++) {
                const float4 hv = h4[q];
                a0.x += whh[0][4*q+0]*hv.x; a0.y += whh[0][4*q+1]*hv.y; a0.z += whh[0][4*q+2]*hv.z; a0.w += whh[0][4*q+3]*hv.w;
                a1.x += whh[1][4*q+0]*hv.x; a1.y += whh[1][4*q+1]*hv.y; a1.z += whh[1][4*q+2]*hv.z; a1.w += whh[1][4*q+3]*hv.w;
                a2.x += whh[2][4*q+0]*hv.x; a2.y += whh[2][4*q+1]*hv.y; a2.z += whh[2][4*q+2]*hv.z; a2.w += whh[2][4*q+3]*hv.w;
                a3.x += whh[3][4*q+0]*hv.x; a3.y += whh[3][4*q+1]*hv.y; a3.z += whh[3][4*q+2]*hv.z; a3.w += whh[3][4*q+3]*hv.w;
            }
        }
        float occa = 0.f, occb = 0.f;
#pragma unroll
        for (int i = 0; i < 6; i++) { occa += oa[i]; occb += ob[i]; }
        while (m2) {   // rare: >6 occupied cells
            const int j = __ffsll((long long)m2) - 1;
            m2 &= m2 - 1;
            occa += wtb[j * 512];
            occb += wtb[j * 512 + 128];
        }
        float pg0 = biasg[0] + (a0.x + a0.y) + (a0.z + a0.w) + ((ch == 0) ? occa : 0.0f);
        float pg1 = biasg[1] + (a1.x + a1.y) + (a1.z + a1.w) + ((ch == 0) ? occb : 0.0f);
        float pg2 = biasg[2] + (a2.x + a2.y) + (a2.z + a2.w) + ((ch == 1) ? occa : 0.0f);
        float pg3 = biasg[3] + (a3.x + a3.y) + (a3.z + a3.w) + ((ch == 1) ? occb : 0.0f);
        pg0 += __shfl_xor(pg0, 32);
        pg1 += __shfl_xor(pg1, 32);
        pg2 += __shfl_xor(pg2, 32);
        pg3 += __shfl_xor(pg3, 32);

        const float gi = sigm(pg0), gf = sigm(pg1);
        const float gg = tanh_(pg2), go = sigm(pg3);
        c = gf * c + gi * gg;
        const float h = go * tanh_(c);
        if (ch == 0) hbuf[p ^ 1][u] = h;

        float t0 = wo0 * h, t1 = wo1 * h, t2 = wo2 * h, t3 = wo3 * h, t4 = wo4 * h;
#pragma unroll
        for (int off = 16; off > 0; off >>= 1) {
            t0 += __shfl_down(t0, off); t1 += __shfl_down(t1, off);
            t2 += __shfl_down(t2, off); t3 += __shfl_down(t3, off);
            t4 += __shfl_down(t4, off);
        }
        if (lane == 0) {
            red2[0][wv] = t0; red2[1][wv] = t1; red2[2][wv] = t2;
            red2[3][wv] = t3; red2[4][wv] = t4;
        }
        bar();   // B2: h + red ready

        const float4 r0 = ((const float4*)red2)[0];
        const float4 r1 = ((const float4*)red2)[1];
        const float n0 = (r0.x + r0.y) + (r0.z + r0.w) + bo0;
        const float n1 = (r1.x + r1.y) + (r1.z + r1.w) + bo1;
        if (tid < 5) {
            const float4 r = ((const float4*)red2)[tid];
            out[(S1 + s) * 5 + tid] = (r.x + r.y) + (r.z + r.w) + boT;
        }
        dx = n0; dy = n1;            // pc - pp for next step's embedding
        pcx += n0; pcy += n1;        // new predicted center (uniform registers)
        p ^= 1;
    }
}

// ---------- launcher ----------
extern "C" void kernel_launch(void* const* d_in, const int* in_sizes, int n_in,
                              void* d_out, int out_size, void* d_ws, size_t ws_size,
                              hipStream_t stream) {
    const float* obs   = (const float*)d_in[0];
    const float* oth   = (const float*)d_in[1];
    const float* W_emb = (const float*)d_in[2];
    const float* b_emb = (const float*)d_in[3];
    const float* W_ih  = (const float*)d_in[4];
    const float* b_ih  = (const float*)d_in[5];
    const float* W_hh  = (const float*)d_in[6];
    const float* b_hh  = (const float*)d_in[7];
    const float* W_out = (const float*)d_in[8];
    const float* b_out = (const float*)d_in[9];
    float* out = (float*)d_out;

    unsigned long long* occm = (unsigned long long*)d_ws;
    float* G1 = (float*)((char*)d_ws + 16384);
    float* WT = (float*)((char*)d_ws + 16384 + (size_t)S1 * 512 * 4);

    k_occ1<<<S1, 256, 0, stream>>>(obs, oth, occm);
    k_tr<<<36, 512, 0, stream>>>(W_ih, WT);
    k_g1<<<S1, 256, 0, stream>>>(obs, W_emb, b_emb, W_ih, b_ih, b_hh, occm, G1);
    k_seq<<<1, 256, 0, stream>>>(obs, oth, W_emb, b_emb, W_ih, b_ih, W_hh, b_hh,
                                 W_out, b_out, G1, WT, out);
}

// Round 3
// 14159.735 us; speedup vs baseline: 1.1783x; 1.1783x over previous
//
#include <hip/hip_runtime.h>

#define NN   4096
#define OBSN 2048
#define S1   2047
#define S2   2047
#define HID  128
#define INDIM 100

typedef float v2f __attribute__((ext_vector_type(2)));
typedef float v4f __attribute__((ext_vector_type(4)));

// Barrier WITHOUT vmcnt(0) drain: all cross-thread per-step dataflow is LDS,
// so lgkmcnt(0) suffices; global prefetches stay in flight across steps.
__device__ __forceinline__ void bar() {
    asm volatile("s_waitcnt lgkmcnt(0)\n\ts_barrier" ::: "memory");
}

__device__ __forceinline__ float sigm(float x) {
    return 1.0f / (1.0f + __expf(-x));
}
__device__ __forceinline__ float tanh_(float x) {
    float e = __expf(2.0f * x);
    return 1.0f - 2.0f / (e + 1.0f);
}

// Exact reference-semantics cell classification (strict < both sides,
// boundary-equality excluded via a+b==7). bx[j] = CST[j]+cx EXACTLY as ref.
__device__ __forceinline__ unsigned long long classify(float x, float y,
                                                       const float* bx, const float* by) {
    int a = 0, b = 0, c = 0, d = 0;
#pragma unroll
    for (int j = 0; j < 7; j++) {
        a += bx[j] < x;
        b += x < bx[j];
        c += by[j] < y;
        d += y < by[j];
    }
    if (a >= 1 && a <= 6 && (a + b) == 7 && c >= 1 && c <= 6 && (c + d) == 7)
        return 1ull << ((a - 1) * 6 + (c - 1));
    return 0ull;
}

__device__ __forceinline__ float hsum8(const float* p8) {
    const v4f a = ((const v4f*)p8)[0];
    const v4f b = ((const v4f*)p8)[1];
    return ((a.x + a.y) + (a.z + a.w)) + ((b.x + b.y) + (b.z + b.w));
}

// ---------- kernel 1: phase-1 occupancy masks (parallel over t) ----------
__global__ __launch_bounds__(256) void k_occ1(const float* __restrict__ obs,
                                              const float* __restrict__ oth,
                                              unsigned long long* __restrict__ occm) {
    const int t = blockIdx.x;
    const int slice = t + 1;
    const float cx = obs[slice * 2 + 0];
    const float cy = obs[slice * 2 + 1];
    const float CST[7] = {-1.5f, -1.0f, -0.5f, 0.0f, 0.5f, 1.0f, 1.5f};
    float bx[7], by[7];
#pragma unroll
    for (int j = 0; j < 7; j++) { bx[j] = CST[j] + cx; by[j] = CST[j] + cy; }

    const float2* p = (const float2*)(oth + (size_t)slice * NN * 2);
    unsigned long long m = 0ull;
#pragma unroll 4
    for (int i = 0; i < 16; i++) {
        float2 q = p[i * 256 + threadIdx.x];
        if (q.x > bx[0] && q.x < bx[6] && q.y > by[0] && q.y < by[6])
            m |= classify(q.x, q.y, bx, by);
    }
#pragma unroll
    for (int off = 32; off > 0; off >>= 1) m |= __shfl_down(m, off);
    __shared__ unsigned long long sm[4];
    if ((threadIdx.x & 63) == 0) sm[threadIdx.x >> 6] = m;
    __syncthreads();
    if (threadIdx.x == 0) occm[t] = sm[0] | sm[1] | sm[2] | sm[3];
}

// ---------- kernel 2: transpose occ columns of W_ih into [36][512] ----------
__global__ void k_tr(const float* __restrict__ W_ih, float* __restrict__ WT) {
    WT[blockIdx.x * 512 + threadIdx.x] = W_ih[threadIdx.x * INDIM + 64 + blockIdx.x];
}

// ---------- kernel 3: phase-1 gate preactivation G1[t][512] ----------
__global__ __launch_bounds__(256) void k_g1(const float* __restrict__ obs,
                                            const float* __restrict__ W_emb,
                                            const float* __restrict__ b_emb,
                                            const float* __restrict__ W_ih,
                                            const float* __restrict__ b_ih,
                                            const float* __restrict__ b_hh,
                                            const unsigned long long* __restrict__ occm,
                                            float* __restrict__ G1) {
    const int t = blockIdx.x;
    const int tid = threadIdx.x;
    __shared__ __align__(16) float e[64];
    const float d0 = obs[(t + 1) * 2 + 0] - obs[t * 2 + 0];
    const float d1 = obs[(t + 1) * 2 + 1] - obs[t * 2 + 1];
    if (tid < 64) {
        float v = W_emb[tid * 2 + 0] * d0 + W_emb[tid * 2 + 1] * d1 + b_emb[tid];
        e[tid] = v > 0.0f ? v : 0.0f;
    }
    __syncthreads();
    const unsigned long long m = occm[t];
#pragma unroll
    for (int rr = 0; rr < 2; rr++) {
        const int r = tid + rr * 256;
        const float* wr = W_ih + r * INDIM;
        float s = b_ih[r] + b_hh[r];
        float4 acc = {0.f, 0.f, 0.f, 0.f};
        const float4* w4 = (const float4*)wr;
        const float4* e4 = (const float4*)e;
#pragma unroll
        for (int q = 0; q < 16; q++) {
            float4 w = w4[q], ev = e4[q];
            acc.x += w.x * ev.x; acc.y += w.y * ev.y;
            acc.z += w.z * ev.z; acc.w += w.w * ev.w;
        }
        s += (acc.x + acc.y) + (acc.z + acc.w);
        unsigned long long mm = m;
        while (mm) {
            int j = __ffsll((long long)mm) - 1;
            mm &= mm - 1;
            s += wr[64 + j];
        }
        G1[t * 512 + r] = s;
    }
}

// ---------- kernel 4: sequential LSTM ----------
// 512 threads = 8 waves = 2 waves/SIMD (TLP!). lane bits: k = lane&3 (col
// quarter), lane bits 2-5 = unit-within-wave. Thread owns unit u = wv*16 +
// (lane>>2), all 4 gate rows {u+128g}, h-cols [32k,32k+32), emb-cols
// [16k,16k+16). Quad butterfly (shfl_xor 1,2) completes each gate; all 4
// k-threads then hold identical gates -> redundant consistent c,h.
__global__ __launch_bounds__(512, 2) void k_seq(const float* __restrict__ obs,
                                                const float* __restrict__ oth,
                                                const float* __restrict__ W_emb,
                                                const float* __restrict__ b_emb,
                                                const float* __restrict__ W_ih,
                                                const float* __restrict__ b_ih,
                                                const float* __restrict__ W_hh,
                                                const float* __restrict__ b_hh,
                                                const float* __restrict__ W_out,
                                                const float* __restrict__ b_out,
                                                const float* __restrict__ G1,
                                                const float* __restrict__ WT,
                                                float* __restrict__ out) {
    const int tid  = threadIdx.x;
    const int wv   = tid >> 6;
    const int lane = tid & 63;
    const int u    = wv * 16 + (lane >> 2);
    const int k    = lane & 3;

    // --- persistent W_hh fragment: rows u+128g, cols [32k, 32k+32) ---
    v2f whh[4][16];
#pragma unroll
    for (int g = 0; g < 4; g++) {
        const v2f* src = (const v2f*)(W_hh + (u + 128 * g) * HID + 32 * k);
#pragma unroll
        for (int j = 0; j < 16; j++) whh[g][j] = src[j];
    }
    float biasg[4];   // phase-2 only (phase-1 bias lives inside G1)
#pragma unroll
    for (int g = 0; g < 4; g++) biasg[g] = b_ih[u + 128 * g] + b_hh[u + 128 * g];

    const float woA = W_out[k * HID + u];          // this thread's out-dim = k
    const float woB = W_out[4 * HID + u];          // dim 4, used by k==0 lanes
    const float bo0 = b_out[0], bo1 = b_out[1];
    const float boT = (tid < 5) ? b_out[tid] : 0.0f;
    float we0 = 0.f, we1 = 0.f, be = 0.f;
    if (tid < 64) { we0 = W_emb[tid * 2]; we1 = W_emb[tid * 2 + 1]; be = b_emb[tid]; }
    const float obsA0 = obs[(S1 - 1) * 2], obsA1 = obs[(S1 - 1) * 2 + 1];
    const float obsB0 = obs[S1 * 2],       obsB1 = obs[S1 * 2 + 1];

    __shared__ __align__(16) float hbuf[2][HID];
    __shared__ __align__(16) float e_lds[64];
    __shared__ __align__(16) float red1[2][5][8];
    __shared__ __align__(16) float red2[5][8];
    __shared__ unsigned long long smask[8];

    if (tid < HID) hbuf[0][tid] = 0.0f;
    float c = 0.0f;
    float p1x = 0.f, p1y = 0.f, p2x = 0.f, p2y = 0.f;
    int p = 0;
    __syncthreads();

    // G1 prefetch for t=0 (rows u+128g; same addr across the quad -> merged)
    v4f g1v;
    {
        const float* gp = G1 + u;
        g1v.x = gp[0]; g1v.y = gp[128]; g1v.z = gp[256]; g1v.w = gp[384];
    }

    // =============== phase 1: 1 barrier/step ===============
    for (int t = 0; t < S1; ++t) {
        const v4f cur = g1v;
        const int tn = (t + 1 < S1) ? t + 1 : t;
        {
            const float* gp = G1 + tn * 512 + u;
            g1v.x = gp[0]; g1v.y = gp[128]; g1v.z = gp[256]; g1v.w = gp[384];
        }

        v2f a0 = {0.f, 0.f}, a1 = {0.f, 0.f}, a2 = {0.f, 0.f}, a3 = {0.f, 0.f};
        const v4f* h4 = ((const v4f*)hbuf[p]) + k * 8;
#pragma unroll
        for (int q = 0; q < 8; q++) {
            const v4f hv = h4[q];
            const v2f hl = hv.xy, hh2 = hv.zw;
            a0 = whh[0][2*q] * hl + a0;  a0 = whh[0][2*q+1] * hh2 + a0;
            a1 = whh[1][2*q] * hl + a1;  a1 = whh[1][2*q+1] * hh2 + a1;
            a2 = whh[2][2*q] * hl + a2;  a2 = whh[2][2*q+1] * hh2 + a2;
            a3 = whh[3][2*q] * hl + a3;  a3 = whh[3][2*q+1] * hh2 + a3;
        }
        float pg0 = (a0.x + a0.y) + ((k == 0) ? cur.x : 0.0f);
        float pg1 = (a1.x + a1.y) + ((k == 0) ? cur.y : 0.0f);
        float pg2 = (a2.x + a2.y) + ((k == 0) ? cur.z : 0.0f);
        float pg3 = (a3.x + a3.y) + ((k == 0) ? cur.w : 0.0f);
        pg0 += __shfl_xor(pg0, 1); pg0 += __shfl_xor(pg0, 2);
        pg1 += __shfl_xor(pg1, 1); pg1 += __shfl_xor(pg1, 2);
        pg2 += __shfl_xor(pg2, 1); pg2 += __shfl_xor(pg2, 2);
        pg3 += __shfl_xor(pg3, 1); pg3 += __shfl_xor(pg3, 2);

        const float gi = sigm(pg0), gf = sigm(pg1);
        const float gG = tanh_(pg2), go = sigm(pg3);
        c = gf * c + gi * gG;
        const float h = go * tanh_(c);
        if (k == 0) hbuf[p ^ 1][u] = h;

        float pd = woA * h;
        float pe = (k == 0) ? woB * h : 0.0f;
#pragma unroll
        for (int off = 4; off <= 32; off <<= 1) {
            pd += __shfl_xor(pd, off);
            pe += __shfl_xor(pe, off);
        }
        if (lane < 4)  red1[p][lane][wv] = pd;
        if (lane == 0) red1[p][4][wv] = pe;
        bar();
        if (tid < 5) out[t * 5 + tid] = hsum8(red1[p][tid]) + boT;
        if (t >= S1 - 2) {     // uniform branch: handoff positions to all threads
            const float n0 = hsum8(red1[p][0]) + bo0;
            const float n1 = hsum8(red1[p][1]) + bo1;
            if (t == S1 - 2) { p1x = obsA0 + n0; p1y = obsA1 + n1; }
            else             { p2x = obsB0 + n0; p2y = obsB1 + n1; }
        }
        p ^= 1;
    }

    // --- phase-2-only weights loaded here to split register lifetimes ---
    v2f wie[4][8];
#pragma unroll
    for (int g = 0; g < 4; g++) {
        const v2f* src = (const v2f*)(W_ih + (u + 128 * g) * INDIM + 16 * k);
#pragma unroll
        for (int j = 0; j < 8; j++) wie[g][j] = src[j];
    }

    float pcx = p2x, pcy = p2y;
    float dx = p2x - p1x, dy = p2y - p1y;

    v4f nb[4];   // 8 neighbor points per thread
    {
        const v4f* s0 = (const v4f*)(oth + (size_t)OBSN * NN * 2);
#pragma unroll
        for (int i = 0; i < 4; i++) nb[i] = s0[i * 512 + tid];
    }
    if (tid < 64) {   // e for s=0; visible after first bar (B1)
        float v = we0 * dx + we1 * dy + be;
        e_lds[tid] = v > 0.0f ? v : 0.0f;
    }
    const float CST[7] = {-1.5f, -1.0f, -0.5f, 0.0f, 0.5f, 1.0f, 1.5f};

    // =============== phase 2: 2 barriers/step ===============
    for (int s = 0; s < S2; ++s) {
        float bx[7], by[7];
#pragma unroll
        for (int j = 0; j < 7; j++) { bx[j] = CST[j] + pcx; by[j] = CST[j] + pcy; }

        unsigned long long m = 0ull;
#pragma unroll
        for (int i = 0; i < 4; i++) {
            const v4f q = nb[i];
            if (q.x > bx[0] && q.x < bx[6] && q.y > by[0] && q.y < by[6])
                m |= classify(q.x, q.y, bx, by);
            if (q.z > bx[0] && q.z < bx[6] && q.w > by[0] && q.w < by[6])
                m |= classify(q.z, q.w, bx, by);
        }
        {   // next-slice prefetch; lgkm-only barriers never drain it
            const int sn = (s + 1 < S2) ? s + 1 : s;
            const v4f* pf = (const v4f*)(oth + (size_t)(OBSN + sn) * NN * 2);
#pragma unroll
            for (int i = 0; i < 4; i++) nb[i] = pf[i * 512 + tid];
        }
#pragma unroll
        for (int off = 1; off < 64; off <<= 1) m |= __shfl_xor(m, off);
        if (lane == 0) smask[wv] = m;
        bar();   // B1: smask + e_lds ready

        const unsigned long long mm = smask[0] | smask[1] | smask[2] | smask[3] |
                                      smask[4] | smask[5] | smask[6] | smask[7];
        // occupied-cell W_ih columns, spread across the quad by (idx&3)==k;
        // contributions fold into pg via the same quad butterfly as the dots.
        float og0 = (k == 0) ? biasg[0] : 0.0f;
        float og1 = (k == 0) ? biasg[1] : 0.0f;
        float og2 = (k == 0) ? biasg[2] : 0.0f;
        float og3 = (k == 0) ? biasg[3] : 0.0f;
        {
            unsigned long long mm2 = mm;
            int idx = 0;
            while (mm2) {
                const int j = __ffsll((long long)mm2) - 1;
                mm2 &= mm2 - 1;
                if ((idx & 3) == k) {
                    const float* wc = WT + j * 512 + u;
                    og0 += wc[0];
                    og1 += wc[128];
                    og2 += wc[256];
                    og3 += wc[384];
                }
                idx++;
            }
        }

        v2f a0 = {0.f, 0.f}, a1 = {0.f, 0.f}, a2 = {0.f, 0.f}, a3 = {0.f, 0.f};
        {
            const v4f* e4 = ((const v4f*)e_lds) + k * 4;
#pragma unroll
            for (int q = 0; q < 4; q++) {
                const v4f ev = e4[q];
                const v2f el = ev.xy, eh = ev.zw;
                a0 = wie[0][2*q] * el + a0;  a0 = wie[0][2*q+1] * eh + a0;
                a1 = wie[1][2*q] * el + a1;  a1 = wie[1][2*q+1] * eh + a1;
                a2 = wie[2][2*q] * el + a2;  a2 = wie[2][2*q+1] * eh + a2;
                a3 = wie[3][2*q] * el + a3;  a3 = wie[3][2*q+1] * eh + a3;
            }
            const v4f* h4 = ((const v4f*)hbuf[p]) + k * 8;
#pragma unroll
            for (int q = 0; q < 8; q++) {
                const v4f hv = h4[q];
                const v2f hl = hv.xy, hh2 = hv.zw;
                a0 = whh[0][2*q] * hl + a0;  a0 = whh[0][2*q+1] * hh2 + a0;
                a1 = whh[1][2*q] * hl + a1;  a1 = whh[1][2*q+1] * hh2 + a1;
                a2 = whh[2][2*q] * hl + a2;  a2 = whh[2][2*q+1] * hh2 + a2;
                a3 = whh[3][2*q] * hl + a3;  a3 = whh[3][2*q+1] * hh2 + a3;
            }
        }
        float pg0 = og0 + (a0.x + a0.y);
        float pg1 = og1 + (a1.x + a1.y);
        float pg2 = og2 + (a2.x + a2.y);
        float pg3 = og3 + (a3.x + a3.y);
        pg0 += __shfl_xor(pg0, 1); pg0 += __shfl_xor(pg0, 2);
        pg1 += __shfl_xor(pg1, 1); pg1 += __shfl_xor(pg1, 2);
        pg2 += __shfl_xor(pg2, 1); pg2 += __shfl_xor(pg2, 2);
        pg3 += __shfl_xor(pg3, 1); pg3 += __shfl_xor(pg3, 2);

        const float gi = sigm(pg0), gf = sigm(pg1);
        const float gG = tanh_(pg2), go = sigm(pg3);
        c = gf * c + gi * gG;
        const float h = go * tanh_(c);
        if (k == 0) hbuf[p ^ 1][u] = h;

        float pd = woA * h;
        float pe = (k == 0) ? woB * h : 0.0f;
#pragma unroll
        for (int off = 4; off <= 32; off <<= 1) {
            pd += __shfl_xor(pd, off);
            pe += __shfl_xor(pe, off);
        }
        if (lane < 4)  red2[lane][wv] = pd;
        if (lane == 0) red2[4][wv] = pe;
        bar();   // B2: h + red ready

        const float n0 = hsum8(red2[0]) + bo0;
        const float n1 = hsum8(red2[1]) + bo1;
        if (tid < 5) out[(S1 + s) * 5 + tid] = hsum8(red2[tid]) + boT;
        dx = n0; dy = n1;
        pcx += n0; pcy += n1;
        if (tid < 64) {   // e for s+1; ordered vs this step's readers by B2
            float v = we0 * dx + we1 * dy + be;
            e_lds[tid] = v > 0.0f ? v : 0.0f;
        }
        p ^= 1;
    }
}

// ---------- launcher ----------
extern "C" void kernel_launch(void* const* d_in, const int* in_sizes, int n_in,
                              void* d_out, int out_size, void* d_ws, size_t ws_size,
                              hipStream_t stream) {
    const float* obs   = (const float*)d_in[0];
    const float* oth   = (const float*)d_in[1];
    const float* W_emb = (const float*)d_in[2];
    const float* b_emb = (const float*)d_in[3];
    const float* W_ih  = (const float*)d_in[4];
    const float* b_ih  = (const float*)d_in[5];
    const float* W_hh  = (const float*)d_in[6];
    const float* b_hh  = (const float*)d_in[7];
    const float* W_out = (const float*)d_in[8];
    const float* b_out = (const float*)d_in[9];
    float* out = (float*)d_out;

    unsigned long long* occm = (unsigned long long*)d_ws;
    float* G1 = (float*)((char*)d_ws + 16384);
    float* WT = (float*)((char*)d_ws + 16384 + (size_t)S1 * 512 * 4);

    k_occ1<<<S1, 256, 0, stream>>>(obs, oth, occm);
    k_tr<<<36, 512, 0, stream>>>(W_ih, WT);
    k_g1<<<S1, 256, 0, stream>>>(obs, W_emb, b_emb, W_ih, b_ih, b_hh, occm, G1);
    k_seq<<<1, 512, 0, stream>>>(obs, oth, W_emb, b_emb, W_ih, b_ih, W_hh, b_hh,
                                 W_out, b_out, G1, WT, out);
}